// Round 15
// baseline (408.787 us; speedup 1.0000x reference)
//
#include <hip/hip_runtime.h>
#include <hip/hip_bf16.h>

#define N_NODES 10000
#define N_EDGES 160000

typedef _Float16 h8 __attribute__((ext_vector_type(8)));
typedef _Float16 h4 __attribute__((ext_vector_type(4)));
typedef float f32x4 __attribute__((ext_vector_type(4)));

__device__ __forceinline__ float silu_f(float v){ return v / (1.f + expf(-v)); }

// ---------------------------------------------------------------- K0: prep transposes + WC16T + edge count (merged)
__global__ __launch_bounds__(256) void k_pre(const float* __restrict__ Wr2,
                                             const float* __restrict__ Wr3,
                                             const float* __restrict__ Wr4,
                                             const float* __restrict__ Wup,
                                             const float* __restrict__ Wlin,
                                             const float* __restrict__ Wskip,
                                             const int* __restrict__ eidx,
                                             _Float16* __restrict__ Wr2T,
                                             _Float16* __restrict__ Wr3T,
                                             _Float16* __restrict__ Wr4T,
                                             _Float16* __restrict__ WupT,
                                             _Float16* __restrict__ WC16T,
                                             int* __restrict__ cnt){
  const int b = blockIdx.x;
  __shared__ float wl[128];
  if (b < 224){
    const int idx = b*256 + threadIdx.x;
    if (idx < 4096){
      const int n = idx >> 6, k = idx & 63;
      Wr2T[idx] = (_Float16)(Wr2[k*64 + n] * 0.125f);
    } else if (idx < 8192){
      const int j = idx - 4096;
      const int n = j >> 6, k = j & 63;
      Wr3T[j] = (_Float16)(Wr3[k*64 + n] * 0.125f);
    } else if (idx < 40960){
      const int j = idx - 8192;
      const int n = j >> 6, k = j & 63;
      Wr4T[j] = (_Float16)(Wr4[k*512 + n] * 0.125f);
    } else if (idx < 57344){
      const int j = idx - 40960;
      const int u = j >> 7, k = j & 127;
      WupT[j] = (_Float16)(Wup[k*128 + u] * 0.08838834764831843f);
    }
  } else if (b < 736){
    const int lu = b - 224;                 // l*128 + u
    const int l  = lu >> 7, u = lu & 127;
    if (threadIdx.x < 128) wl[threadIdx.x] = Wlin[lu*128 + threadIdx.x];
    __syncthreads();
    const float* Wsk = Wskip + (size_t)l * 163840;   // [v][a][w]
    for (int i = threadIdx.x; i < 1280; i += 256){   // i = a*128 + w
      float acc = 0.f;
      #pragma unroll 16
      for (int v = 0; v < 128; ++v) acc += wl[v] * Wsk[v*1280 + i];
      const int a = i >> 7, w = i & 127;
      WC16T[((size_t)l*128 + w)*1280 + a*128 + u] =
          (_Float16)(acc * 0.0024705294220065465f);  // 1/sqrt(128*1280)
    }
  } else {
    const int e = (b - 736)*256 + threadIdx.x;
    if (e < N_EDGES) atomicAdd(&cnt[eidx[N_EDGES + e]], 1);
  }
}

// ---------------------------------------------------------------- scan
__global__ __launch_bounds__(256) void k_scan(const int* __restrict__ cnt,
                                              int* __restrict__ off,
                                              int* __restrict__ cur){
  __shared__ int sums[256];
  const int t = threadIdx.x;
  const int base = t * 40;
  int s = 0;
  for (int i = 0; i < 40; ++i){
    const int idx = base + i;
    if (idx < N_NODES) s += cnt[idx];
  }
  sums[t] = s;
  __syncthreads();
  for (int st = 1; st < 256; st <<= 1){
    const int v = (t >= st) ? sums[t - st] : 0;
    __syncthreads();
    sums[t] += v;
    __syncthreads();
  }
  int pre = (t > 0) ? sums[t - 1] : 0;
  for (int i = 0; i < 40; ++i){
    const int idx = base + i;
    if (idx < N_NODES){
      off[idx] = pre; cur[idx] = pre;
      pre += cnt[idx];
    }
  }
  if (t == 255) off[N_NODES] = sums[255];
}

// ---------------------------------------------------------------- K_mid: bucket+gather (0..624) + node_up (625..781)
__global__ __launch_bounds__(256) void k_mid(const int* __restrict__ eidx,
                                             const float* __restrict__ ef,
                                             const float* __restrict__ ea,
                                             int* __restrict__ cur,
                                             int* __restrict__ esnd,
                                             float* __restrict__ efp,
                                             float* __restrict__ eap,
                                             const float* __restrict__ nf,
                                             const _Float16* __restrict__ WupT,
                                             float* __restrict__ x){
  const int b = blockIdx.x;
  const int tid = threadIdx.x;
  alignas(16) __shared__ _Float16 s_nf[64*128];
  alignas(16) __shared__ _Float16 s_wt[128*128];

  if (b < 625){
    const int e = b * 256 + tid;
    if (e < N_EDGES){
      const int pos = atomicAdd(&cur[eidx[N_EDGES + e]], 1);
      esnd[pos] = eidx[e];
      const float4* efs = (const float4*)(ef + (size_t)e*8);
      float4* efd = (float4*)(efp + (size_t)pos*8);
      efd[0] = efs[0]; efd[1] = efs[1];
      const float4* eas = (const float4*)(ea + (size_t)e*16);
      float4* ead = (float4*)(eap + (size_t)pos*16);
      ead[0] = eas[0]; ead[1] = eas[1]; ead[2] = eas[2]; ead[3] = eas[3];
    }
    return;
  }

  const int n0 = (b - 625) * 64;
  {
    const int rl = tid >> 2, part = tid & 3;
    const int gr = n0 + rl;
    #pragma unroll
    for (int j = 0; j < 4; ++j){
      const int cu = part*4 + j;
      h8 hv = (h8){};
      if (gr < N_NODES){
        const float4 v0 = *(const float4*)(nf + (size_t)gr*128 + cu*8);
        const float4 v1 = *(const float4*)(nf + (size_t)gr*128 + cu*8 + 4);
        hv[0]=(_Float16)v0.x; hv[1]=(_Float16)v0.y; hv[2]=(_Float16)v0.z; hv[3]=(_Float16)v0.w;
        hv[4]=(_Float16)v1.x; hv[5]=(_Float16)v1.y; hv[6]=(_Float16)v1.z; hv[7]=(_Float16)v1.w;
      }
      const int cs = (cu & 8) | ((cu & 7) ^ (rl & 7));
      *(h8*)&s_nf[rl*128 + cs*8] = hv;
    }
  }
  {
    const int rl = tid >> 1, part = tid & 1;
    #pragma unroll
    for (int j = 0; j < 8; ++j){
      const int cu = part*8 + j;
      const h8 v = *(const h8*)&WupT[(size_t)rl*128 + cu*8];
      const int cs = (cu & 8) | ((cu & 7) ^ (rl & 7));
      *(h8*)&s_wt[rl*128 + cs*8] = v;
    }
  }
  __syncthreads();

  const int wid = tid >> 6, lane = tid & 63;
  const int li = lane & 15, kg = lane >> 4;

  f32x4 acc[8];
  #pragma unroll
  for (int i = 0; i < 8; ++i) acc[i] = (f32x4){0,0,0,0};

  const int row = wid*16 + li;
  #pragma unroll
  for (int s = 0; s < 4; ++s){
    const int ca = s*4 + kg;
    const int csA = (ca & 8) | ((ca & 7) ^ (row & 7));
    const h8 af = *(const h8*)&s_nf[row*128 + csA*8];
    #pragma unroll
    for (int nt = 0; nt < 8; ++nt){
      const int u = nt*16 + li;
      const int csB = (ca & 8) | ((ca & 7) ^ (u & 7));
      const h8 bf = *(const h8*)&s_wt[u*128 + csB*8];
      acc[nt] = __builtin_amdgcn_mfma_f32_16x16x32_f16(af, bf, acc[nt], 0, 0, 0);
    }
  }
  #pragma unroll
  for (int nt = 0; nt < 8; ++nt){
    #pragma unroll
    for (int r = 0; r < 4; ++r){
      const int gr = n0 + wid*16 + kg*4 + r;
      if (gr < N_NODES) x[(size_t)gr*128 + nt*16 + li] = acc[nt][r];
    }
  }
}

// ---------------------------------------------------------------- K2: FUSED edge MLP + gather v5:
// r13 skeleton (T14 dbuf staging, single-pass tpw, 5 barriers/group) with the
// per-node accumulate moved to MFMA: msg[sk][c] = sum_s shT[sk][s] * w2T[c][s],
// node masking folded into A-fragments. Wave wid owns l = wid channels.
__global__ __launch_bounds__(256) void k_fused(const float* __restrict__ efp,
                                               const float* __restrict__ eap,
                                               const float* __restrict__ x,
                                               const float* __restrict__ Wr1,
                                               const float* __restrict__ Wd,
                                               const _Float16* __restrict__ Wr2T,
                                               const _Float16* __restrict__ Wr3T,
                                               const _Float16* __restrict__ Wr4T,
                                               const float* __restrict__ Wsin,
                                               const int* __restrict__ off,
                                               const int* __restrict__ esnd,
                                               _Float16* __restrict__ msg16){
  const int n0 = blockIdx.x * 4;
  const int tid = threadIdx.x;
  const int lane = tid & 63, wid = tid >> 6;
  const int li = lane & 15, kg = lane >> 4;
  const int u = tid & 127, h = tid >> 7;

  __shared__ float s_ef[2][32][8];
  __shared__ float s_w1[8][64];
  alignas(16) __shared__ _Float16 s_xs[2][32][132];
  alignas(16) __shared__ _Float16 s_actA[32][64];
  alignas(16) __shared__ _Float16 s_actB[32][64];
  alignas(16) __shared__ _Float16 s_w2T[512][40];   // [channel][slot], 80B rows (16B-mult)
  alignas(16) __shared__ _Float16 s_shT[2][16][40]; // [buf][sk][slot]
  __shared__ float s_dd[32];
  __shared__ float s_rho[4];
  __shared__ int   s_offs[5];
  __shared__ float s_emb[4][32];
  __shared__ float s_demb[4][128];

  if (tid < 5) s_offs[tid] = off[n0 + tid];
  if (tid < 4) s_rho[tid] = 0.f;
  for (int j = tid; j < 512; j += 256) s_w1[j >> 6][j & 63] = Wr1[j];
  __syncthreads();

  const int beg = s_offs[0], end = s_offs[4];
  const int ngrp = (end - beg + 31) >> 5;

  const int e8 = tid >> 3, i8 = tid & 7;       // staging: 8 threads/edge
  const int slotB = tid >> 4, jjB = tid & 15;  // sh staging: 16 threads/slot x2

  // persistent MFMA accumulators: node x (8 c-tiles of this wave's 128 channels)
  f32x4 acc0[8], acc1[8], acc2[8], acc3[8];
  #pragma unroll
  for (int t = 0; t < 8; ++t){
    acc0[t] = (f32x4){0,0,0,0}; acc1[t] = (f32x4){0,0,0,0};
    acc2[t] = (f32x4){0,0,0,0}; acc3[t] = (f32x4){0,0,0,0};
  }

  // ---- prologue: stage group 0 into buf 0
  if (ngrp > 0){
    const int p = beg + e8;
    s_ef[0][e8][i8] = (p < end) ? efp[(size_t)p*8 + i8] : 0.f;
    const int pB0 = beg + slotB, pB1 = beg + slotB + 16;
    s_shT[0][jjB][slotB]      = (pB0 < end) ? (_Float16)eap[(size_t)pB0*16 + jjB] : (_Float16)0.f;
    s_shT[0][jjB][slotB + 16] = (pB1 < end) ? (_Float16)eap[(size_t)pB1*16 + jjB] : (_Float16)0.f;
    const int snd = (p < end) ? esnd[p] : 0;
    const float4* xp = (const float4*)(x + (size_t)snd*128 + i8*16);
    #pragma unroll
    for (int j = 0; j < 4; ++j){
      const float4 v = xp[j];
      h4 hv; hv[0]=(_Float16)v.x; hv[1]=(_Float16)v.y; hv[2]=(_Float16)v.z; hv[3]=(_Float16)v.w;
      *(h4*)&s_xs[0][e8][i8*16 + j*4] = hv;
    }
  }
  __syncthreads();

  for (int g = 0; g < ngrp; ++g){
    const int cur = g & 1, nxt = cur ^ 1;
    const int pbase  = beg + g*32;
    const int pbase2 = pbase + 32;
    const bool more = (g + 1 < ngrp);

    // ---- ISSUE next-group direct loads (efp, eap, esnd)
    float ef_r = 0.f, sh_r0 = 0.f, sh_r1 = 0.f;
    int snd_r = 0;
    const int pA = pbase2 + e8;
    const bool vA = more && (pA < end);
    if (vA){ ef_r = efp[(size_t)pA*8 + i8]; snd_r = esnd[pA]; }
    const int pB0 = pbase2 + slotB, pB1 = pbase2 + slotB + 16;
    if (more && pB0 < end) sh_r0 = eap[(size_t)pB0*16 + jjB];
    if (more && pB1 < end) sh_r1 = eap[(size_t)pB1*16 + jjB];

    // ---- dd
    if (tid < 32){
      float s = 0.f;
      #pragma unroll
      for (int i = 0; i < 8; ++i) s += s_ef[cur][tid][i] * Wd[i];
      s_dd[tid] = tanhf(s*s);
    }

    // ---- L1 (VALU, K=8): 32e x 64n
    {
      const int e = tid >> 3, ng = tid & 7;
      float hv[8] = {0,0,0,0,0,0,0,0};
      #pragma unroll
      for (int k = 0; k < 8; ++k){
        const float ev = s_ef[cur][e][k] * 0.3535533905932738f;
        #pragma unroll
        for (int j = 0; j < 8; ++j) hv[j] += ev * s_w1[k][ng*8 + j];
      }
      h8 o;
      #pragma unroll
      for (int j = 0; j < 8; ++j) o[j] = (_Float16)silu_f(hv[j]);
      *(h8*)&s_actA[e][(ng ^ (e & 7))*8] = o;
    }
    __syncthreads();

    // ---- L2 MFMA
    {
      h8 af[2];
      #pragma unroll
      for (int s = 0; s < 2; ++s)
        af[s] = *(const h8*)&Wr2T[(size_t)(wid*16 + li)*64 + s*32 + kg*8];
      #pragma unroll
      for (int nt = 0; nt < 2; ++nt){
        const int e = nt*16 + li;
        f32x4 acc = (f32x4){0,0,0,0};
        #pragma unroll
        for (int s = 0; s < 2; ++s){
          const h8 bf = *(const h8*)&s_actA[e][((s*4 + kg) ^ (e & 7))*8];
          acc = __builtin_amdgcn_mfma_f32_16x16x32_f16(af[s], bf, acc, 0, 0, 0);
        }
        #pragma unroll
        for (int r = 0; r < 4; ++r){
          const int n = wid*16 + kg*4 + r;
          s_actB[e][((n >> 3) ^ (e & 7))*8 + (n & 7)] = (_Float16)silu_f(acc[r]);
        }
      }
    }
    __syncthreads();

    // ---- ISSUE next-group xs loads
    float4 xs_r0 = {0,0,0,0}, xs_r1 = {0,0,0,0}, xs_r2 = {0,0,0,0}, xs_r3 = {0,0,0,0};
    if (vA){
      const float4* xp = (const float4*)(x + (size_t)snd_r*128 + i8*16);
      xs_r0 = xp[0]; xs_r1 = xp[1]; xs_r2 = xp[2]; xs_r3 = xp[3];
    }

    // ---- L3 MFMA
    {
      h8 af[2];
      #pragma unroll
      for (int s = 0; s < 2; ++s)
        af[s] = *(const h8*)&Wr3T[(size_t)(wid*16 + li)*64 + s*32 + kg*8];
      #pragma unroll
      for (int nt = 0; nt < 2; ++nt){
        const int e = nt*16 + li;
        f32x4 acc = (f32x4){0,0,0,0};
        #pragma unroll
        for (int s = 0; s < 2; ++s){
          const h8 bf = *(const h8*)&s_actB[e][((s*4 + kg) ^ (e & 7))*8];
          acc = __builtin_amdgcn_mfma_f32_16x16x32_f16(af[s], bf, acc, 0, 0, 0);
        }
        #pragma unroll
        for (int r = 0; r < 4; ++r){
          const int n = wid*16 + kg*4 + r;
          s_actA[e][((n >> 3) ^ (e & 7))*8 + (n & 7)] = (_Float16)silu_f(acc[r]);
        }
      }
    }
    __syncthreads();

    // ---- tpw MFMA: 512c x 32e -> s_w2T[c][s] = tpw*xs (transposed scalar writes)
    {
      h8 bf[2][2];
      #pragma unroll
      for (int nt = 0; nt < 2; ++nt){
        const int e = nt*16 + li;
        #pragma unroll
        for (int s = 0; s < 2; ++s)
          bf[nt][s] = *(const h8*)&s_actA[e][((s*4 + kg) ^ (e & 7))*8];
      }
      #pragma unroll
      for (int p = 0; p < 2; ++p){
        #pragma unroll
        for (int mt = 0; mt < 4; ++mt){
          const int nbase = wid*128 + p*64 + mt*16;
          h8 af[2];
          #pragma unroll
          for (int s = 0; s < 2; ++s)
            af[s] = *(const h8*)&Wr4T[(size_t)(nbase + li)*64 + s*32 + kg*8];
          f32x4 acc[2];
          #pragma unroll
          for (int nt = 0; nt < 2; ++nt){
            acc[nt] = (f32x4){0,0,0,0};
            #pragma unroll
            for (int s = 0; s < 2; ++s)
              acc[nt] = __builtin_amdgcn_mfma_f32_16x16x32_f16(af[s], bf[nt][s], acc[nt], 0, 0, 0);
          }
          const int c0 = nbase + kg*4;
          const int u0 = c0 & 127;
          #pragma unroll
          for (int nt = 0; nt < 2; ++nt){
            const int e = nt*16 + li;
            const h4 xv = *(const h4*)&s_xs[cur][e][u0];
            #pragma unroll
            for (int r = 0; r < 4; ++r)
              s_w2T[c0 + r][e] = (_Float16)acc[nt][r] * xv[r];
          }
        }
      }
    }
    __syncthreads();

    // ---- slot ranges per node
    int lo0 = s_offs[0] - pbase; lo0 = lo0 < 0 ? 0 : lo0;
    int hi0 = s_offs[1] - pbase; hi0 = hi0 > 32 ? 32 : (hi0 < 0 ? 0 : hi0);
    int lo1 = s_offs[1] - pbase; lo1 = lo1 < 0 ? 0 : lo1;
    int hi1 = s_offs[2] - pbase; hi1 = hi1 > 32 ? 32 : (hi1 < 0 ? 0 : hi1);
    int lo2 = s_offs[2] - pbase; lo2 = lo2 < 0 ? 0 : lo2;
    int hi2 = s_offs[3] - pbase; hi2 = hi2 > 32 ? 32 : (hi2 < 0 ? 0 : hi2);
    int lo3 = s_offs[3] - pbase; lo3 = lo3 < 0 ? 0 : lo3;
    int hi3 = s_offs[4] - pbase; hi3 = hi3 > 32 ? 32 : (hi3 < 0 ? 0 : hi3);

    // ---- ACC as MFMA: af = shT row (all 16 sk), masked per node; bf = w2T rows
    {
      const h8 afF = *(const h8*)&s_shT[cur][li][kg*8];
      h8 af0 = afF, af1 = afF, af2 = afF, af3 = afF;
      #pragma unroll
      for (int j = 0; j < 8; ++j){
        const int slot = kg*8 + j;
        if (slot < lo0 || slot >= hi0) af0[j] = (_Float16)0.f;
        if (slot < lo1 || slot >= hi1) af1[j] = (_Float16)0.f;
        if (slot < lo2 || slot >= hi2) af2[j] = (_Float16)0.f;
        if (slot < lo3 || slot >= hi3) af3[j] = (_Float16)0.f;
      }
      #pragma unroll
      for (int t = 0; t < 8; ++t){
        const h8 bf = *(const h8*)&s_w2T[wid*128 + t*16 + li][kg*8];
        acc0[t] = __builtin_amdgcn_mfma_f32_16x16x32_f16(af0, bf, acc0[t], 0, 0, 0);
        acc1[t] = __builtin_amdgcn_mfma_f32_16x16x32_f16(af1, bf, acc1[t], 0, 0, 0);
        acc2[t] = __builtin_amdgcn_mfma_f32_16x16x32_f16(af2, bf, acc2[t], 0, 0, 0);
        acc3[t] = __builtin_amdgcn_mfma_f32_16x16x32_f16(af3, bf, acc3[t], 0, 0, 0);
      }
    }

    if (tid < 4){
      int lo = s_offs[tid]     - pbase; lo = lo < 0 ? 0 : lo;
      int hi = s_offs[tid + 1] - pbase; hi = hi > 32 ? 32 : (hi < 0 ? 0 : hi);
      float r = 0.f;
      for (int s = lo; s < hi; ++s) r += s_dd[s];
      s_rho[tid] += r;
    }

    // ---- WRITE next-group stage buffers
    if (more){
      s_ef[nxt][e8][i8] = ef_r;
      s_shT[nxt][jjB][slotB]      = (_Float16)sh_r0;
      s_shT[nxt][jjB][slotB + 16] = (_Float16)sh_r1;
      const float4 xr[4] = {xs_r0, xs_r1, xs_r2, xs_r3};
      #pragma unroll
      for (int j = 0; j < 4; ++j){
        h4 hv; hv[0]=(_Float16)xr[j].x; hv[1]=(_Float16)xr[j].y;
        hv[2]=(_Float16)xr[j].z; hv[3]=(_Float16)xr[j].w;
        *(h4*)&s_xs[nxt][e8][i8*16 + j*4] = hv;
      }
    }
    __syncthreads();
  }

  // ---- epilogue: rho -> emb -> demb; fragment writes
  if (tid < 64){
    const int ni = tid >> 4, f = tid & 15;
    const float fr  = expf(-0.28782313662425572f * (float)f);  // ln(100)/16
    const float ang = s_rho[ni] * fr;
    s_emb[ni][f]      = sinf(ang);
    s_emb[ni][f + 16] = cosf(ang);
  }
  __syncthreads();
  if (h == 0){
    float db0 = 0.f, db1 = 0.f, db2 = 0.f, db3 = 0.f;
    #pragma unroll 8
    for (int j = 0; j < 32; ++j){
      const float wsv = Wsin[j*128 + u];
      db0 += s_emb[0][j]*wsv; db1 += s_emb[1][j]*wsv;
      db2 += s_emb[2][j]*wsv; db3 += s_emb[3][j]*wsv;
    }
    s_demb[0][u] = db0; s_demb[1][u] = db1;
    s_demb[2][u] = db2; s_demb[3][u] = db3;
  }
  __syncthreads();

  const float t0 = 1.f/(s_rho[0]+1.f), t1 = 1.f/(s_rho[1]+1.f);
  const float t2 = 1.f/(s_rho[2]+1.f), t3 = 1.f/(s_rho[3]+1.f);
  const int OFFl = (wid==0) ? 0 : (wid==1) ? 1 : (wid==2) ? 4 : 9;
  const int Dl   = 2*wid + 1;

  #pragma unroll
  for (int t = 0; t < 8; ++t){
    const int uu = t*16 + li;
    #pragma unroll
    for (int r = 0; r < 4; ++r){
      const int sk = kg*4 + r;
      if (sk >= OFFl && sk < OFFl + Dl){
        const size_t base = (size_t)sk*128 + uu;
        float v0 = acc0[t][r]*t0, v1 = acc1[t][r]*t1;
        float v2 = acc2[t][r]*t2, v3 = acc3[t][r]*t3;
        if (wid == 0 && sk == 0){
          v0 += s_demb[0][uu]; v1 += s_demb[1][uu];
          v2 += s_demb[2][uu]; v3 += s_demb[3][uu];
        }
        msg16[(size_t)(n0+0)*2048 + base] = (_Float16)v0;
        msg16[(size_t)(n0+1)*2048 + base] = (_Float16)v1;
        msg16[(size_t)(n0+2)*2048 + base] = (_Float16)v2;
        msg16[(size_t)(n0+3)*2048 + base] = (_Float16)v3;
      }
    }
  }
}

// ---------------------------------------------------------------- K4: final GEMM body, 512 threads / 8 waves (fp16 A source, fp16 outD)
template<int L, int D>
__device__ __forceinline__ void final_body(const int bb,
                                           const _Float16* __restrict__ msg16,
                                           const float* __restrict__ attrs,
                                           const _Float16* __restrict__ WC16T,
                                           _Float16* __restrict__ outD,
                                           _Float16* __restrict__ sA,
                                           _Float16* __restrict__ sB,      // [2][64*128]
                                           _Float16* __restrict__ sAttr){
  constexpr int OFF  = (L==0 ? 0 : L==1 ? 1 : L==2 ? 4 : 9);
  constexpr int ROWS = N_NODES * D;
  const int r0  = bb * 128;
  const int tid = threadIdx.x;

  {
    const int rl = tid >> 2, quarter = tid & 3;
    const int gr = r0 + rl;
    h8 vals[4];
    if (gr < ROWS){
      const int n = gr / D, k = gr - n*D;
      const _Float16* src = msg16 + (size_t)n*2048 + (size_t)(OFF+k)*128 + quarter*32;
      #pragma unroll
      for (int j = 0; j < 4; ++j) vals[j] = *(const h8*)(src + j*8);
    } else {
      #pragma unroll
      for (int j = 0; j < 4; ++j) vals[j] = (h8){};
    }
    #pragma unroll
    for (int j = 0; j < 4; ++j){
      const int cu = quarter*4 + j;
      const int cs = (cu & 8) | ((cu & 7) ^ (rl & 7));
      *(h8*)&sA[rl*128 + cs*8] = vals[j];
    }
  }
  for (int i = tid; i < 1280; i += 512){
    const int rl = i / 10, aa = i - rl*10;
    const int gr = r0 + rl;
    sAttr[i] = (gr < ROWS) ? (_Float16)attrs[(gr / D)*10 + aa] : (_Float16)0.f;
  }
  {
    const int w = tid >> 2, part = tid & 3;
    const _Float16* src = WC16T + ((size_t)L*128 + w)*1280 + part*16;
    #pragma unroll
    for (int j = 0; j < 2; ++j){
      const h8 v = *(const h8*)(src + j*8);
      const int cc = part*2 + j;
      *(h8*)&sB[w*64 + (cc ^ (w & 7))*8] = v;
    }
  }
  __syncthreads();

  const int wid = tid >> 6, lane = tid & 63;
  const int wm = wid >> 2, wn = wid & 3;
  const int li = lane & 15, kg = lane >> 4;

  f32x4 acc[4][2];
  #pragma unroll
  for (int m = 0; m < 4; ++m)
    #pragma unroll
    for (int nn = 0; nn < 2; ++nn) acc[m][nn] = (f32x4){0,0,0,0};

  for (int step = 0; step < 20; ++step){
    _Float16* sbc = (step & 1) ? (sB + 8192) : sB;
    _Float16* sbn = (step & 1) ? sB : (sB + 8192);
    const bool more = (step + 1 < 20);
    h8 pre[2];
    if (more){
      const int a2 = (step+1) >> 1, u02 = ((step+1) & 1) << 6;
      const _Float16* src = WC16T + ((size_t)L*128 + (tid>>2))*1280 + a2*128 + u02 + (tid&3)*16;
      #pragma unroll
      for (int j = 0; j < 2; ++j) pre[j] = *(const h8*)(src + j*8);
    }

    const int a  = step >> 1;
    const int uh = (step & 1) << 3;

    h8 afr[4][2], bfr[2][2];
    #pragma unroll
    for (int m = 0; m < 4; ++m){
      const int row = wm*64 + m*16 + li;
      const _Float16 av = sAttr[row*10 + a];
      h8 avx;
      #pragma unroll
      for (int j = 0; j < 8; ++j) avx[j] = av;
      #pragma unroll
      for (int s = 0; s < 2; ++s){
        const int ca = uh + s*4 + kg;
        const int cs = (ca & 8) | ((ca & 7) ^ (row & 7));
        const h8 mA = *(const h8*)&sA[row*128 + cs*8];
        afr[m][s] = mA * avx;
      }
    }
    #pragma unroll
    for (int nn = 0; nn < 2; ++nn){
      const int w = wn*32 + nn*16 + li;
      #pragma unroll
      for (int s = 0; s < 2; ++s){
        const int cb = s*4 + kg;
        bfr[nn][s] = *(const h8*)&sbc[w*64 + ((cb ^ (w & 7)))*8];
      }
    }
    #pragma unroll
    for (int s = 0; s < 2; ++s)
      #pragma unroll
      for (int m = 0; m < 4; ++m)
        #pragma unroll
        for (int nn = 0; nn < 2; ++nn)
          acc[m][nn] = __builtin_amdgcn_mfma_f32_16x16x32_f16(afr[m][s], bfr[nn][s], acc[m][nn], 0, 0, 0);

    if (more){
      const int w = tid >> 2, part = tid & 3;
      #pragma unroll
      for (int j = 0; j < 2; ++j){
        const int cc = part*2 + j;
        *(h8*)&sbn[w*64 + (cc ^ (w & 7))*8] = pre[j];
      }
    }
    __syncthreads();
  }

  #pragma unroll
  for (int m = 0; m < 4; ++m){
    const int rbase = r0 + wm*64 + m*16 + kg*4;
    #pragma unroll
    for (int rr = 0; rr < 4; ++rr){
      const int gr = rbase + rr;
      if (gr < ROWS){
        _Float16* op = outD + (size_t)gr*128;
        #pragma unroll
        for (int nn = 0; nn < 2; ++nn)
          op[wn*32 + nn*16 + li] = (_Float16)acc[m][nn][rr];
      }
    }
  }
}

__global__ __launch_bounds__(512) void k_final_all(const _Float16* __restrict__ msg16,
                                                   const float* __restrict__ attrs,
                                                   const _Float16* __restrict__ WC16T,
                                                   _Float16* __restrict__ outD){
  alignas(16) __shared__ _Float16 sA[128*128];
  alignas(16) __shared__ _Float16 sB[2*64*128];
  __shared__ _Float16 sAttr[128*10];
  const int b = blockIdx.x;
  if (b < 79)       final_body<0,1>(b,       msg16, attrs, WC16T, outD,            sA, sB, sAttr);
  else if (b < 314) final_body<1,3>(b - 79,  msg16, attrs, WC16T, outD + 1280000,  sA, sB, sAttr);
  else if (b < 705) final_body<2,5>(b - 314, msg16, attrs, WC16T, outD + 5120000,  sA, sB, sAttr);
  else              final_body<3,7>(b - 705, msg16, attrs, WC16T, outD + 11520000, sA, sB, sAttr);
}

// ---------------------------------------------------------------- K5: merge fp16 outD_l into f32 out[n][w][sk] full lines
__global__ __launch_bounds__(256) void k_merge(const _Float16* __restrict__ outD,
                                               float* __restrict__ out){
  const int n0 = blockIdx.x * 4;
  const int tid = threadIdx.x;
  __shared__ float lds[4*16*132];   // [nloc][sk][w] stride 132

#define MERGE_LOAD(SRC, CHUNKS, ROWS_PER_N, SKOFF)                       \
  { const _Float16* src = (SRC);                                         \
    for (int j = tid; j < (CHUNKS); j += 256){                           \
      const int row = j >> 4, c8 = j & 15;                               \
      const int nloc = row / (ROWS_PER_N), k = row - nloc*(ROWS_PER_N);  \
      const h8 v = *(const h8*)(src + (size_t)row*128 + c8*8);           \
      float* dst = &lds[(nloc*16 + (SKOFF) + k)*132 + c8*8];             \
      dst[0]=(float)v[0]; dst[1]=(float)v[1]; dst[2]=(float)v[2];        \
      dst[3]=(float)v[3]; dst[4]=(float)v[4]; dst[5]=(float)v[5];        \
      dst[6]=(float)v[6]; dst[7]=(float)v[7];                            \
    } }

  MERGE_LOAD(outD + (size_t)n0*128,                 64,  1, 0)
  MERGE_LOAD(outD + 1280000 + (size_t)n0*3*128,    192,  3, 1)
  MERGE_LOAD(outD + 5120000 + (size_t)n0*5*128,    320,  5, 4)
  MERGE_LOAD(outD + 11520000 + (size_t)n0*7*128,   448,  7, 9)
  __syncthreads();

  for (int j = tid; j < 2048; j += 256){
    const int nloc = j >> 9, qv = j & 511;
    const int w = qv >> 2, s0 = (qv & 3) << 2;
    float4 v;
    v.x = lds[(nloc*16 + s0 + 0)*132 + w];
    v.y = lds[(nloc*16 + s0 + 1)*132 + w];
    v.z = lds[(nloc*16 + s0 + 2)*132 + w];
    v.w = lds[(nloc*16 + s0 + 3)*132 + w];
    *(float4*)&out[(size_t)(n0 + nloc)*2048 + qv*4] = v;
  }
}

// ----------------------------------------------------------------
extern "C" void kernel_launch(void* const* d_in, const int* in_sizes, int n_in,
                              void* d_out, int out_size, void* d_ws, size_t ws_size,
                              hipStream_t stream){
  const float* node_attrs = (const float*)d_in[0];
  const float* node_feats = (const float*)d_in[1];
  const float* edge_attrs = (const float*)d_in[2];
  const float* edge_feats = (const float*)d_in[3];
  const int*   edge_index = (const int*)d_in[4];
  const float* W_up  = (const float*)d_in[5];
  const float* Wr1   = (const float*)d_in[6];
  const float* Wr2   = (const float*)d_in[7];
  const float* Wr3   = (const float*)d_in[8];
  const float* Wr4   = (const float*)d_in[9];
  const float* Wd    = (const float*)d_in[10];
  const float* Wsin  = (const float*)d_in[11];
  const float* Wlin  = (const float*)d_in[12];
  const float* Wskip = (const float*)d_in[13];
  float* out = (float*)d_out;

  _Float16* outD  = (_Float16*)d_ws;                // 20,480,000 halfs
  _Float16* msg16 = outD + 20480000;                // 20,480,000 halfs
  float* x        = (float*)(msg16 + 20480000);     //  1,280,000 f32
  _Float16* WC16T = (_Float16*)(x + 1280000);       //    655,360 halfs
  int* cnt   = (int*)(WC16T + 655360);              //     10,000
  int* off   = cnt + 10000;                         //     10,016
  int* cur   = off + 10016;                         //     10,000
  int* esnd  = cur + 10000;                         //    160,000
  float* efp = (float*)(esnd + 160000);             //  1,280,000 f32
  float* eap = efp + 1280000;                       //  2,560,000 f32
  _Float16* Wr2T = (_Float16*)(eap + 2560000);      //      4,096 halfs
  _Float16* Wr3T = Wr2T + 4096;                     //      4,096 halfs
  _Float16* Wr4T = Wr3T + 4096;                     //     32,768 halfs
  _Float16* WupT = Wr4T + 32768;                    //     16,384 halfs

  hipMemsetAsync(cnt, 0, (size_t)10000 * sizeof(int), stream);

  k_pre<<<1361, 256, 0, stream>>>(Wr2, Wr3, Wr4, W_up, Wlin, Wskip, edge_index,
                                  Wr2T, Wr3T, Wr4T, WupT, WC16T, cnt);
  k_scan<<<1, 256, 0, stream>>>(cnt, off, cur);
  k_mid<<<782, 256, 0, stream>>>(edge_index, edge_feats, edge_attrs,
                                 cur, esnd, efp, eap,
                                 node_feats, WupT, x);

  k_fused<<<N_NODES/4, 256, 0, stream>>>(efp, eap, x,
                                         Wr1, Wd, Wr2T, Wr3T, Wr4T, Wsin,
                                         off, esnd, msg16);

  k_final_all<<<1252, 512, 0, stream>>>(msg16, node_attrs, WC16T, outD);

  k_merge<<<2500, 256, 0, stream>>>(outD, out);
}

// Round 16
// 299.549 us; speedup vs baseline: 1.3647x; 1.3647x over previous
//
#include <hip/hip_runtime.h>
#include <hip/hip_bf16.h>

#define N_NODES 10000
#define N_EDGES 160000

typedef _Float16 h8 __attribute__((ext_vector_type(8)));
typedef _Float16 h4 __attribute__((ext_vector_type(4)));
typedef float f32x4 __attribute__((ext_vector_type(4)));

__device__ __forceinline__ float silu_f(float v){ return v / (1.f + expf(-v)); }

// ---------------------------------------------------------------- K0: prep transposes + WC16T + edge count (merged)
__global__ __launch_bounds__(256) void k_pre(const float* __restrict__ Wr2,
                                             const float* __restrict__ Wr3,
                                             const float* __restrict__ Wr4,
                                             const float* __restrict__ Wup,
                                             const float* __restrict__ Wlin,
                                             const float* __restrict__ Wskip,
                                             const int* __restrict__ eidx,
                                             _Float16* __restrict__ Wr2T,
                                             _Float16* __restrict__ Wr3T,
                                             _Float16* __restrict__ Wr4T,
                                             _Float16* __restrict__ WupT,
                                             _Float16* __restrict__ WC16T,
                                             int* __restrict__ cnt){
  const int b = blockIdx.x;
  __shared__ float wl[128];
  if (b < 224){
    const int idx = b*256 + threadIdx.x;
    if (idx < 4096){
      const int n = idx >> 6, k = idx & 63;
      Wr2T[idx] = (_Float16)(Wr2[k*64 + n] * 0.125f);
    } else if (idx < 8192){
      const int j = idx - 4096;
      const int n = j >> 6, k = j & 63;
      Wr3T[j] = (_Float16)(Wr3[k*64 + n] * 0.125f);
    } else if (idx < 40960){
      const int j = idx - 8192;
      const int n = j >> 6, k = j & 63;
      Wr4T[j] = (_Float16)(Wr4[k*512 + n] * 0.125f);
    } else if (idx < 57344){
      const int j = idx - 40960;
      const int u = j >> 7, k = j & 127;
      WupT[j] = (_Float16)(Wup[k*128 + u] * 0.08838834764831843f);
    }
  } else if (b < 736){
    const int lu = b - 224;                 // l*128 + u
    const int l  = lu >> 7, u = lu & 127;
    if (threadIdx.x < 128) wl[threadIdx.x] = Wlin[lu*128 + threadIdx.x];
    __syncthreads();
    const float* Wsk = Wskip + (size_t)l * 163840;   // [v][a][w]
    for (int i = threadIdx.x; i < 1280; i += 256){   // i = a*128 + w
      float acc = 0.f;
      #pragma unroll 16
      for (int v = 0; v < 128; ++v) acc += wl[v] * Wsk[v*1280 + i];
      const int a = i >> 7, w = i & 127;
      WC16T[((size_t)l*128 + w)*1280 + a*128 + u] =
          (_Float16)(acc * 0.0024705294220065465f);  // 1/sqrt(128*1280)
    }
  } else {
    const int e = (b - 736)*256 + threadIdx.x;
    if (e < N_EDGES) atomicAdd(&cnt[eidx[N_EDGES + e]], 1);
  }
}

// ---------------------------------------------------------------- scan
__global__ __launch_bounds__(256) void k_scan(const int* __restrict__ cnt,
                                              int* __restrict__ off,
                                              int* __restrict__ cur){
  __shared__ int sums[256];
  const int t = threadIdx.x;
  const int base = t * 40;
  int s = 0;
  for (int i = 0; i < 40; ++i){
    const int idx = base + i;
    if (idx < N_NODES) s += cnt[idx];
  }
  sums[t] = s;
  __syncthreads();
  for (int st = 1; st < 256; st <<= 1){
    const int v = (t >= st) ? sums[t - st] : 0;
    __syncthreads();
    sums[t] += v;
    __syncthreads();
  }
  int pre = (t > 0) ? sums[t - 1] : 0;
  for (int i = 0; i < 40; ++i){
    const int idx = base + i;
    if (idx < N_NODES){
      off[idx] = pre; cur[idx] = pre;
      pre += cnt[idx];
    }
  }
  if (t == 255) off[N_NODES] = sums[255];
}

// ---------------------------------------------------------------- K_mid: bucket+gather (0..624) + node_up (625..781)
__global__ __launch_bounds__(256) void k_mid(const int* __restrict__ eidx,
                                             const float* __restrict__ ef,
                                             const float* __restrict__ ea,
                                             int* __restrict__ cur,
                                             int* __restrict__ esnd,
                                             float* __restrict__ efp,
                                             float* __restrict__ eap,
                                             const float* __restrict__ nf,
                                             const _Float16* __restrict__ WupT,
                                             float* __restrict__ x){
  const int b = blockIdx.x;
  const int tid = threadIdx.x;
  alignas(16) __shared__ _Float16 s_nf[64*128];
  alignas(16) __shared__ _Float16 s_wt[128*128];

  if (b < 625){
    const int e = b * 256 + tid;
    if (e < N_EDGES){
      const int pos = atomicAdd(&cur[eidx[N_EDGES + e]], 1);
      esnd[pos] = eidx[e];
      const float4* efs = (const float4*)(ef + (size_t)e*8);
      float4* efd = (float4*)(efp + (size_t)pos*8);
      efd[0] = efs[0]; efd[1] = efs[1];
      const float4* eas = (const float4*)(ea + (size_t)e*16);
      float4* ead = (float4*)(eap + (size_t)pos*16);
      ead[0] = eas[0]; ead[1] = eas[1]; ead[2] = eas[2]; ead[3] = eas[3];
    }
    return;
  }

  const int n0 = (b - 625) * 64;
  {
    const int rl = tid >> 2, part = tid & 3;
    const int gr = n0 + rl;
    #pragma unroll
    for (int j = 0; j < 4; ++j){
      const int cu = part*4 + j;
      h8 hv = (h8){};
      if (gr < N_NODES){
        const float4 v0 = *(const float4*)(nf + (size_t)gr*128 + cu*8);
        const float4 v1 = *(const float4*)(nf + (size_t)gr*128 + cu*8 + 4);
        hv[0]=(_Float16)v0.x; hv[1]=(_Float16)v0.y; hv[2]=(_Float16)v0.z; hv[3]=(_Float16)v0.w;
        hv[4]=(_Float16)v1.x; hv[5]=(_Float16)v1.y; hv[6]=(_Float16)v1.z; hv[7]=(_Float16)v1.w;
      }
      const int cs = (cu & 8) | ((cu & 7) ^ (rl & 7));
      *(h8*)&s_nf[rl*128 + cs*8] = hv;
    }
  }
  {
    const int rl = tid >> 1, part = tid & 1;
    #pragma unroll
    for (int j = 0; j < 8; ++j){
      const int cu = part*8 + j;
      const h8 v = *(const h8*)&WupT[(size_t)rl*128 + cu*8];
      const int cs = (cu & 8) | ((cu & 7) ^ (rl & 7));
      *(h8*)&s_wt[rl*128 + cs*8] = v;
    }
  }
  __syncthreads();

  const int wid = tid >> 6, lane = tid & 63;
  const int li = lane & 15, kg = lane >> 4;

  f32x4 acc[8];
  #pragma unroll
  for (int i = 0; i < 8; ++i) acc[i] = (f32x4){0,0,0,0};

  const int row = wid*16 + li;
  #pragma unroll
  for (int s = 0; s < 4; ++s){
    const int ca = s*4 + kg;
    const int csA = (ca & 8) | ((ca & 7) ^ (row & 7));
    const h8 af = *(const h8*)&s_nf[row*128 + csA*8];
    #pragma unroll
    for (int nt = 0; nt < 8; ++nt){
      const int u = nt*16 + li;
      const int csB = (ca & 8) | ((ca & 7) ^ (u & 7));
      const h8 bf = *(const h8*)&s_wt[u*128 + csB*8];
      acc[nt] = __builtin_amdgcn_mfma_f32_16x16x32_f16(af, bf, acc[nt], 0, 0, 0);
    }
  }
  #pragma unroll
  for (int nt = 0; nt < 8; ++nt){
    #pragma unroll
    for (int r = 0; r < 4; ++r){
      const int gr = n0 + wid*16 + kg*4 + r;
      if (gr < N_NODES) x[(size_t)gr*128 + nt*16 + li] = acc[nt][r];
    }
  }
}

// ---------------------------------------------------------------- K2: FUSED edge MLP + gather (round-13 proven version, 138 us)
__global__ __launch_bounds__(256) void k_fused(const float* __restrict__ efp,
                                               const float* __restrict__ eap,
                                               const float* __restrict__ x,
                                               const float* __restrict__ Wr1,
                                               const float* __restrict__ Wd,
                                               const _Float16* __restrict__ Wr2T,
                                               const _Float16* __restrict__ Wr3T,
                                               const _Float16* __restrict__ Wr4T,
                                               const float* __restrict__ Wsin,
                                               const int* __restrict__ off,
                                               const int* __restrict__ esnd,
                                               _Float16* __restrict__ msg16){
  const int n0 = blockIdx.x * 4;
  const int tid = threadIdx.x;
  const int lane = tid & 63, wid = tid >> 6;
  const int li = lane & 15, kg = lane >> 4;
  const int u = tid & 127, h = tid >> 7;

  __shared__ float s_ef[2][32][8];
  __shared__ float s_w1[8][64];
  alignas(16) __shared__ _Float16 s_xs[2][32][132];
  alignas(16) __shared__ _Float16 s_actA[32][64];
  alignas(16) __shared__ _Float16 s_actB[32][64];
  alignas(16) __shared__ _Float16 s_w2[32][520];
  alignas(16) __shared__ float s_sh[2][32][16];
  __shared__ float s_dd[32];
  __shared__ float s_rho[4];
  __shared__ int   s_offs[5];
  __shared__ float s_emb[4][32];

  if (tid < 5) s_offs[tid] = off[n0 + tid];
  if (tid < 4) s_rho[tid] = 0.f;
  for (int j = tid; j < 512; j += 256) s_w1[j >> 6][j & 63] = Wr1[j];
  __syncthreads();

  const int beg = s_offs[0], end = s_offs[4];
  const int ngrp = (end - beg + 31) >> 5;

  const int e8 = tid >> 3, i8 = tid & 7;       // staging mapping: 8 threads/edge
  const int slotB = tid >> 4, jjB = tid & 15;  // sh mapping: 16 threads/slot (x2 rounds)

  float a0[8] = {0,0,0,0,0,0,0,0};
  float a1[8] = {0,0,0,0,0,0,0,0};
  float a2[8] = {0,0,0,0,0,0,0,0};
  float a3[8] = {0,0,0,0,0,0,0,0};

  // ---- prologue: stage group 0 into buf 0
  if (ngrp > 0){
    const int p = beg + e8;
    s_ef[0][e8][i8] = (p < end) ? efp[(size_t)p*8 + i8] : 0.f;
    const int pB0 = beg + slotB, pB1 = beg + slotB + 16;
    s_sh[0][slotB][jjB]      = (pB0 < end) ? eap[(size_t)pB0*16 + jjB] : 0.f;
    s_sh[0][slotB + 16][jjB] = (pB1 < end) ? eap[(size_t)pB1*16 + jjB] : 0.f;
    const int snd = (p < end) ? esnd[p] : 0;
    const float4* xp = (const float4*)(x + (size_t)snd*128 + i8*16);
    #pragma unroll
    for (int j = 0; j < 4; ++j){
      const float4 v = xp[j];
      h4 hv; hv[0]=(_Float16)v.x; hv[1]=(_Float16)v.y; hv[2]=(_Float16)v.z; hv[3]=(_Float16)v.w;
      *(h4*)&s_xs[0][e8][i8*16 + j*4] = hv;
    }
  }
  __syncthreads();

  for (int g = 0; g < ngrp; ++g){
    const int cur = g & 1, nxt = cur ^ 1;
    const int pbase  = beg + g*32;
    const int pbase2 = pbase + 32;
    const bool more = (g + 1 < ngrp);

    // ---- ISSUE next-group direct loads into registers (efp, eap, esnd)
    float ef_r = 0.f, sh_r0 = 0.f, sh_r1 = 0.f;
    int snd_r = 0;
    const int pA = pbase2 + e8;
    const bool vA = more && (pA < end);
    if (vA){ ef_r = efp[(size_t)pA*8 + i8]; snd_r = esnd[pA]; }
    const int pB0 = pbase2 + slotB, pB1 = pbase2 + slotB + 16;
    if (more && pB0 < end) sh_r0 = eap[(size_t)pB0*16 + jjB];
    if (more && pB1 < end) sh_r1 = eap[(size_t)pB1*16 + jjB];

    // ---- dd (from s_ef[cur])
    if (tid < 32){
      float s = 0.f;
      #pragma unroll
      for (int i = 0; i < 8; ++i) s += s_ef[cur][tid][i] * Wd[i];
      s_dd[tid] = tanhf(s*s);
    }

    // ---- L1 (VALU, K=8): 32e x 64n, thread = (e, 8 n's)
    {
      const int e = tid >> 3, ng = tid & 7;
      float hv[8] = {0,0,0,0,0,0,0,0};
      #pragma unroll
      for (int k = 0; k < 8; ++k){
        const float ev = s_ef[cur][e][k] * 0.3535533905932738f;
        #pragma unroll
        for (int j = 0; j < 8; ++j) hv[j] += ev * s_w1[k][ng*8 + j];
      }
      h8 o;
      #pragma unroll
      for (int j = 0; j < 8; ++j) o[j] = (_Float16)silu_f(hv[j]);
      *(h8*)&s_actA[e][(ng ^ (e & 7))*8] = o;
    }
    __syncthreads();

    // ---- L2 MFMA: 64n x 32e
    {
      h8 af[2];
      #pragma unroll
      for (int s = 0; s < 2; ++s)
        af[s] = *(const h8*)&Wr2T[(size_t)(wid*16 + li)*64 + s*32 + kg*8];
      #pragma unroll
      for (int nt = 0; nt < 2; ++nt){
        const int e = nt*16 + li;
        f32x4 acc = (f32x4){0,0,0,0};
        #pragma unroll
        for (int s = 0; s < 2; ++s){
          const h8 bf = *(const h8*)&s_actA[e][((s*4 + kg) ^ (e & 7))*8];
          acc = __builtin_amdgcn_mfma_f32_16x16x32_f16(af[s], bf, acc, 0, 0, 0);
        }
        #pragma unroll
        for (int r = 0; r < 4; ++r){
          const int n = wid*16 + kg*4 + r;
          s_actB[e][((n >> 3) ^ (e & 7))*8 + (n & 7)] = (_Float16)silu_f(acc[r]);
        }
      }
    }
    __syncthreads();

    // ---- ISSUE next-group xs loads (snd_r now resolved)
    float4 xs_r0 = {0,0,0,0}, xs_r1 = {0,0,0,0}, xs_r2 = {0,0,0,0}, xs_r3 = {0,0,0,0};
    if (vA){
      const float4* xp = (const float4*)(x + (size_t)snd_r*128 + i8*16);
      xs_r0 = xp[0]; xs_r1 = xp[1]; xs_r2 = xp[2]; xs_r3 = xp[3];
    }

    // ---- L3 MFMA
    {
      h8 af[2];
      #pragma unroll
      for (int s = 0; s < 2; ++s)
        af[s] = *(const h8*)&Wr3T[(size_t)(wid*16 + li)*64 + s*32 + kg*8];
      #pragma unroll
      for (int nt = 0; nt < 2; ++nt){
        const int e = nt*16 + li;
        f32x4 acc = (f32x4){0,0,0,0};
        #pragma unroll
        for (int s = 0; s < 2; ++s){
          const h8 bf = *(const h8*)&s_actB[e][((s*4 + kg) ^ (e & 7))*8];
          acc = __builtin_amdgcn_mfma_f32_16x16x32_f16(af[s], bf, acc, 0, 0, 0);
        }
        #pragma unroll
        for (int r = 0; r < 4; ++r){
          const int n = wid*16 + kg*4 + r;
          s_actA[e][((n >> 3) ^ (e & 7))*8 + (n & 7)] = (_Float16)silu_f(acc[r]);
        }
      }
    }
    __syncthreads();

    // ---- tpw MFMA: 512c x 32e -> s_w2 = tpw*xs[cur]
    {
      h8 bf[2][2];
      #pragma unroll
      for (int nt = 0; nt < 2; ++nt){
        const int e = nt*16 + li;
        #pragma unroll
        for (int s = 0; s < 2; ++s)
          bf[nt][s] = *(const h8*)&s_actA[e][((s*4 + kg) ^ (e & 7))*8];
      }
      #pragma unroll
      for (int p = 0; p < 2; ++p){
        #pragma unroll
        for (int mt = 0; mt < 4; ++mt){
          const int nbase = wid*128 + p*64 + mt*16;
          h8 af[2];
          #pragma unroll
          for (int s = 0; s < 2; ++s)
            af[s] = *(const h8*)&Wr4T[(size_t)(nbase + li)*64 + s*32 + kg*8];
          f32x4 acc[2];
          #pragma unroll
          for (int nt = 0; nt < 2; ++nt){
            acc[nt] = (f32x4){0,0,0,0};
            #pragma unroll
            for (int s = 0; s < 2; ++s)
              acc[nt] = __builtin_amdgcn_mfma_f32_16x16x32_f16(af[s], bf[nt][s], acc[nt], 0, 0, 0);
          }
          const int c0 = nbase + kg*4;
          const int u0 = c0 & 127;
          #pragma unroll
          for (int nt = 0; nt < 2; ++nt){
            const int e = nt*16 + li;
            const h4 xv = *(const h4*)&s_xs[cur][e][u0];
            h4 ov;
            #pragma unroll
            for (int r = 0; r < 4; ++r) ov[r] = (_Float16)acc[nt][r] * xv[r];
            *(h4*)&s_w2[e][c0] = ov;
          }
        }
      }
    }
    __syncthreads();

    // ---- accumulate into per-node registers (slot ranges from CSR offsets)
    int lo0 = s_offs[0] - pbase; lo0 = lo0 < 0 ? 0 : lo0;
    int hi0 = s_offs[1] - pbase; hi0 = hi0 > 32 ? 32 : (hi0 < 0 ? 0 : hi0);
    int lo1 = s_offs[1] - pbase; lo1 = lo1 < 0 ? 0 : lo1;
    int hi1 = s_offs[2] - pbase; hi1 = hi1 > 32 ? 32 : (hi1 < 0 ? 0 : hi1);
    int lo2 = s_offs[2] - pbase; lo2 = lo2 < 0 ? 0 : lo2;
    int hi2 = s_offs[3] - pbase; hi2 = hi2 > 32 ? 32 : (hi2 < 0 ? 0 : hi2);
    int lo3 = s_offs[3] - pbase; lo3 = lo3 < 0 ? 0 : lo3;
    int hi3 = s_offs[4] - pbase; hi3 = hi3 > 32 ? 32 : (hi3 < 0 ? 0 : hi3);

#define ACC_H0(A, LO, HI)                                            \
    for (int s = (LO); s < (HI); ++s){                               \
      const float wa  = (float)s_w2[s][u];                           \
      const float wb  = (float)s_w2[s][128 + u];                     \
      const float wcv = (float)s_w2[s][256 + u];                     \
      const float4 sa = *(const float4*)&s_sh[cur][s][0];            \
      const float4 sb = *(const float4*)&s_sh[cur][s][4];            \
      A[0] += wa*sa.x;                                               \
      A[1] += wb*sa.y;  A[2] += wb*sa.z;  A[3] += wb*sa.w;           \
      A[4] += wcv*sb.x; A[5] += wcv*sb.y;                            \
      A[6] += wcv*sb.z; A[7] += wcv*sb.w;                            \
    }
#define ACC_H1(A, LO, HI)                                            \
    for (int s = (LO); s < (HI); ++s){                               \
      const float wcv = (float)s_w2[s][256 + u];                     \
      const float wd  = (float)s_w2[s][384 + u];                     \
      const float4 sa = *(const float4*)&s_sh[cur][s][8];            \
      const float4 sb = *(const float4*)&s_sh[cur][s][12];           \
      A[0] += wcv*sa.x;                                              \
      A[1] += wd*sa.y;  A[2] += wd*sa.z;  A[3] += wd*sa.w;           \
      A[4] += wd*sb.x;  A[5] += wd*sb.y;                             \
      A[6] += wd*sb.z;  A[7] += wd*sb.w;                             \
    }

    if (h == 0){
      ACC_H0(a0, lo0, hi0) ACC_H0(a1, lo1, hi1)
      ACC_H0(a2, lo2, hi2) ACC_H0(a3, lo3, hi3)
    } else {
      ACC_H1(a0, lo0, hi0) ACC_H1(a1, lo1, hi1)
      ACC_H1(a2, lo2, hi2) ACC_H1(a3, lo3, hi3)
    }

    if (tid < 4){
      int lo = s_offs[tid]     - pbase; lo = lo < 0 ? 0 : lo;
      int hi = s_offs[tid + 1] - pbase; hi = hi > 32 ? 32 : (hi < 0 ? 0 : hi);
      float r = 0.f;
      for (int s = lo; s < hi; ++s) r += s_dd[s];
      s_rho[tid] += r;
    }

    // ---- WRITE next-group stage buffers (loads have had ~2000cy to land)
    if (more){
      s_ef[nxt][e8][i8] = ef_r;
      s_sh[nxt][slotB][jjB]      = sh_r0;
      s_sh[nxt][slotB + 16][jjB] = sh_r1;
      const float4 xr[4] = {xs_r0, xs_r1, xs_r2, xs_r3};
      #pragma unroll
      for (int j = 0; j < 4; ++j){
        h4 hv; hv[0]=(_Float16)xr[j].x; hv[1]=(_Float16)xr[j].y;
        hv[2]=(_Float16)xr[j].z; hv[3]=(_Float16)xr[j].w;
        *(h4*)&s_xs[nxt][e8][i8*16 + j*4] = hv;
      }
    }
    __syncthreads();
  }

  // ---- epilogue: per-node rho -> emb, tinv; write msg16 (fp16)
  if (tid < 64){
    const int ni = tid >> 4, f = tid & 15;
    const float fr  = expf(-0.28782313662425572f * (float)f);  // ln(100)/16
    const float ang = s_rho[ni] * fr;
    s_emb[ni][f]      = sinf(ang);
    s_emb[ni][f + 16] = cosf(ang);
  }
  __syncthreads();

  float db0 = 0.f, db1 = 0.f, db2 = 0.f, db3 = 0.f;
  if (h == 0){
    #pragma unroll 8
    for (int j = 0; j < 32; ++j){
      const float wsv = Wsin[j*128 + u];
      db0 += s_emb[0][j]*wsv; db1 += s_emb[1][j]*wsv;
      db2 += s_emb[2][j]*wsv; db3 += s_emb[3][j]*wsv;
    }
  }
  const float t0 = 1.f/(s_rho[0]+1.f), t1 = 1.f/(s_rho[1]+1.f);
  const float t2 = 1.f/(s_rho[2]+1.f), t3 = 1.f/(s_rho[3]+1.f);
  #pragma unroll
  for (int j = 0; j < 8; ++j){
    float v0 = a0[j]*t0, v1 = a1[j]*t1, v2 = a2[j]*t2, v3 = a3[j]*t3;
    if (h == 0 && j == 0){ v0 += db0; v1 += db1; v2 += db2; v3 += db3; }
    const size_t base = (size_t)(h*8 + j)*128 + u;
    msg16[(size_t)(n0+0)*2048 + base] = (_Float16)v0;
    msg16[(size_t)(n0+1)*2048 + base] = (_Float16)v1;
    msg16[(size_t)(n0+2)*2048 + base] = (_Float16)v2;
    msg16[(size_t)(n0+3)*2048 + base] = (_Float16)v3;
  }
}

// ---------------------------------------------------------------- K4: final GEMM body, 512 threads / 8 waves (fp16 A source, fp16 outD)
template<int L, int D>
__device__ __forceinline__ void final_body(const int bb,
                                           const _Float16* __restrict__ msg16,
                                           const float* __restrict__ attrs,
                                           const _Float16* __restrict__ WC16T,
                                           _Float16* __restrict__ outD,
                                           _Float16* __restrict__ sA,
                                           _Float16* __restrict__ sB,      // [2][64*128]
                                           _Float16* __restrict__ sAttr){
  constexpr int OFF  = (L==0 ? 0 : L==1 ? 1 : L==2 ? 4 : 9);
  constexpr int ROWS = N_NODES * D;
  const int r0  = bb * 128;
  const int tid = threadIdx.x;

  {
    const int rl = tid >> 2, quarter = tid & 3;
    const int gr = r0 + rl;
    h8 vals[4];
    if (gr < ROWS){
      const int n = gr / D, k = gr - n*D;
      const _Float16* src = msg16 + (size_t)n*2048 + (size_t)(OFF+k)*128 + quarter*32;
      #pragma unroll
      for (int j = 0; j < 4; ++j) vals[j] = *(const h8*)(src + j*8);
    } else {
      #pragma unroll
      for (int j = 0; j < 4; ++j) vals[j] = (h8){};
    }
    #pragma unroll
    for (int j = 0; j < 4; ++j){
      const int cu = quarter*4 + j;
      const int cs = (cu & 8) | ((cu & 7) ^ (rl & 7));
      *(h8*)&sA[rl*128 + cs*8] = vals[j];
    }
  }
  for (int i = tid; i < 1280; i += 512){
    const int rl = i / 10, aa = i - rl*10;
    const int gr = r0 + rl;
    sAttr[i] = (gr < ROWS) ? (_Float16)attrs[(gr / D)*10 + aa] : (_Float16)0.f;
  }
  {
    const int w = tid >> 2, part = tid & 3;
    const _Float16* src = WC16T + ((size_t)L*128 + w)*1280 + part*16;
    #pragma unroll
    for (int j = 0; j < 2; ++j){
      const h8 v = *(const h8*)(src + j*8);
      const int cc = part*2 + j;
      *(h8*)&sB[w*64 + (cc ^ (w & 7))*8] = v;
    }
  }
  __syncthreads();

  const int wid = tid >> 6, lane = tid & 63;
  const int wm = wid >> 2, wn = wid & 3;
  const int li = lane & 15, kg = lane >> 4;

  f32x4 acc[4][2];
  #pragma unroll
  for (int m = 0; m < 4; ++m)
    #pragma unroll
    for (int nn = 0; nn < 2; ++nn) acc[m][nn] = (f32x4){0,0,0,0};

  for (int step = 0; step < 20; ++step){
    _Float16* sbc = (step & 1) ? (sB + 8192) : sB;
    _Float16* sbn = (step & 1) ? sB : (sB + 8192);
    const bool more = (step + 1 < 20);
    h8 pre[2];
    if (more){
      const int a2 = (step+1) >> 1, u02 = ((step+1) & 1) << 6;
      const _Float16* src = WC16T + ((size_t)L*128 + (tid>>2))*1280 + a2*128 + u02 + (tid&3)*16;
      #pragma unroll
      for (int j = 0; j < 2; ++j) pre[j] = *(const h8*)(src + j*8);
    }

    const int a  = step >> 1;
    const int uh = (step & 1) << 3;

    h8 afr[4][2], bfr[2][2];
    #pragma unroll
    for (int m = 0; m < 4; ++m){
      const int row = wm*64 + m*16 + li;
      const _Float16 av = sAttr[row*10 + a];
      h8 avx;
      #pragma unroll
      for (int j = 0; j < 8; ++j) avx[j] = av;
      #pragma unroll
      for (int s = 0; s < 2; ++s){
        const int ca = uh + s*4 + kg;
        const int cs = (ca & 8) | ((ca & 7) ^ (row & 7));
        const h8 mA = *(const h8*)&sA[row*128 + cs*8];
        afr[m][s] = mA * avx;
      }
    }
    #pragma unroll
    for (int nn = 0; nn < 2; ++nn){
      const int w = wn*32 + nn*16 + li;
      #pragma unroll
      for (int s = 0; s < 2; ++s){
        const int cb = s*4 + kg;
        bfr[nn][s] = *(const h8*)&sbc[w*64 + ((cb ^ (w & 7)))*8];
      }
    }
    #pragma unroll
    for (int s = 0; s < 2; ++s)
      #pragma unroll
      for (int m = 0; m < 4; ++m)
        #pragma unroll
        for (int nn = 0; nn < 2; ++nn)
          acc[m][nn] = __builtin_amdgcn_mfma_f32_16x16x32_f16(afr[m][s], bfr[nn][s], acc[m][nn], 0, 0, 0);

    if (more){
      const int w = tid >> 2, part = tid & 3;
      #pragma unroll
      for (int j = 0; j < 2; ++j){
        const int cc = part*2 + j;
        *(h8*)&sbn[w*64 + (cc ^ (w & 7))*8] = pre[j];
      }
    }
    __syncthreads();
  }

  #pragma unroll
  for (int m = 0; m < 4; ++m){
    const int rbase = r0 + wm*64 + m*16 + kg*4;
    #pragma unroll
    for (int rr = 0; rr < 4; ++rr){
      const int gr = rbase + rr;
      if (gr < ROWS){
        _Float16* op = outD + (size_t)gr*128;
        #pragma unroll
        for (int nn = 0; nn < 2; ++nn)
          op[wn*32 + nn*16 + li] = (_Float16)acc[m][nn][rr];
      }
    }
  }
}

__global__ __launch_bounds__(512) void k_final_all(const _Float16* __restrict__ msg16,
                                                   const float* __restrict__ attrs,
                                                   const _Float16* __restrict__ WC16T,
                                                   _Float16* __restrict__ outD){
  alignas(16) __shared__ _Float16 sA[128*128];
  alignas(16) __shared__ _Float16 sB[2*64*128];
  __shared__ _Float16 sAttr[128*10];
  const int b = blockIdx.x;
  if (b < 79)       final_body<0,1>(b,       msg16, attrs, WC16T, outD,            sA, sB, sAttr);
  else if (b < 314) final_body<1,3>(b - 79,  msg16, attrs, WC16T, outD + 1280000,  sA, sB, sAttr);
  else if (b < 705) final_body<2,5>(b - 314, msg16, attrs, WC16T, outD + 5120000,  sA, sB, sAttr);
  else              final_body<3,7>(b - 705, msg16, attrs, WC16T, outD + 11520000, sA, sB, sAttr);
}

// ---------------------------------------------------------------- K5: merge fp16 outD_l into f32 out[n][w][sk] full lines
__global__ __launch_bounds__(256) void k_merge(const _Float16* __restrict__ outD,
                                               float* __restrict__ out){
  const int n0 = blockIdx.x * 4;
  const int tid = threadIdx.x;
  __shared__ float lds[4*16*132];   // [nloc][sk][w] stride 132

#define MERGE_LOAD(SRC, CHUNKS, ROWS_PER_N, SKOFF)                       \
  { const _Float16* src = (SRC);                                         \
    for (int j = tid; j < (CHUNKS); j += 256){                           \
      const int row = j >> 4, c8 = j & 15;                               \
      const int nloc = row / (ROWS_PER_N), k = row - nloc*(ROWS_PER_N);  \
      const h8 v = *(const h8*)(src + (size_t)row*128 + c8*8);           \
      float* dst = &lds[(nloc*16 + (SKOFF) + k)*132 + c8*8];             \
      dst[0]=(float)v[0]; dst[1]=(float)v[1]; dst[2]=(float)v[2];        \
      dst[3]=(float)v[3]; dst[4]=(float)v[4]; dst[5]=(float)v[5];        \
      dst[6]=(float)v[6]; dst[7]=(float)v[7];                            \
    } }

  MERGE_LOAD(outD + (size_t)n0*128,                 64,  1, 0)
  MERGE_LOAD(outD + 1280000 + (size_t)n0*3*128,    192,  3, 1)
  MERGE_LOAD(outD + 5120000 + (size_t)n0*5*128,    320,  5, 4)
  MERGE_LOAD(outD + 11520000 + (size_t)n0*7*128,   448,  7, 9)
  __syncthreads();

  for (int j = tid; j < 2048; j += 256){
    const int nloc = j >> 9, qv = j & 511;
    const int w = qv >> 2, s0 = (qv & 3) << 2;
    float4 v;
    v.x = lds[(nloc*16 + s0 + 0)*132 + w];
    v.y = lds[(nloc*16 + s0 + 1)*132 + w];
    v.z = lds[(nloc*16 + s0 + 2)*132 + w];
    v.w = lds[(nloc*16 + s0 + 3)*132 + w];
    *(float4*)&out[(size_t)(n0 + nloc)*2048 + qv*4] = v;
  }
}

// ----------------------------------------------------------------
extern "C" void kernel_launch(void* const* d_in, const int* in_sizes, int n_in,
                              void* d_out, int out_size, void* d_ws, size_t ws_size,
                              hipStream_t stream){
  const float* node_attrs = (const float*)d_in[0];
  const float* node_feats = (const float*)d_in[1];
  const float* edge_attrs = (const float*)d_in[2];
  const float* edge_feats = (const float*)d_in[3];
  const int*   edge_index = (const int*)d_in[4];
  const float* W_up  = (const float*)d_in[5];
  const float* Wr1   = (const float*)d_in[6];
  const float* Wr2   = (const float*)d_in[7];
  const float* Wr3   = (const float*)d_in[8];
  const float* Wr4   = (const float*)d_in[9];
  const float* Wd    = (const float*)d_in[10];
  const float* Wsin  = (const float*)d_in[11];
  const float* Wlin  = (const float*)d_in[12];
  const float* Wskip = (const float*)d_in[13];
  float* out = (float*)d_out;

  _Float16* outD  = (_Float16*)d_ws;                // 20,480,000 halfs
  _Float16* msg16 = outD + 20480000;                // 20,480,000 halfs
  float* x        = (float*)(msg16 + 20480000);     //  1,280,000 f32
  _Float16* WC16T = (_Float16*)(x + 1280000);       //    655,360 halfs
  int* cnt   = (int*)(WC16T + 655360);              //     10,000
  int* off   = cnt + 10000;                         //     10,016
  int* cur   = off + 10016;                         //     10,000
  int* esnd  = cur + 10000;                         //    160,000
  float* efp = (float*)(esnd + 160000);             //  1,280,000 f32
  float* eap = efp + 1280000;                       //  2,560,000 f32
  _Float16* Wr2T = (_Float16*)(eap + 2560000);      //      4,096 halfs
  _Float16* Wr3T = Wr2T + 4096;                     //      4,096 halfs
  _Float16* Wr4T = Wr3T + 4096;                     //     32,768 halfs
  _Float16* WupT = Wr4T + 32768;                    //     16,384 halfs

  hipMemsetAsync(cnt, 0, (size_t)10000 * sizeof(int), stream);

  k_pre<<<1361, 256, 0, stream>>>(Wr2, Wr3, Wr4, W_up, Wlin, Wskip, edge_index,
                                  Wr2T, Wr3T, Wr4T, WupT, WC16T, cnt);
  k_scan<<<1, 256, 0, stream>>>(cnt, off, cur);
  k_mid<<<782, 256, 0, stream>>>(edge_index, edge_feats, edge_attrs,
                                 cur, esnd, efp, eap,
                                 node_feats, WupT, x);

  k_fused<<<N_NODES/4, 256, 0, stream>>>(efp, eap, x,
                                         Wr1, Wd, Wr2T, Wr3T, Wr4T, Wsin,
                                         off, esnd, msg16);

  k_final_all<<<1252, 512, 0, stream>>>(msg16, node_attrs, WC16T, outD);

  k_merge<<<2500, 256, 0, stream>>>(outD, out);
}